// Round 4
// baseline (916.610 us; speedup 1.0000x reference)
//
#include <hip/hip_runtime.h>
#include <hip/hip_bf16.h>

typedef __bf16 bf16;
typedef __attribute__((ext_vector_type(8))) __bf16 bf16x8;
typedef __attribute__((ext_vector_type(4))) float floatx4;

// B=8, N=4096, DM=1024, H=16, G=4, D=64; rows = 32768
// Inputs fp32; compute bf16 MFMA; output fp32.
// qkv layout: [row][3200] = q(0..1023)|k(1024..2047)|v(2048..3071)|qa(3072..3135)|pad

__device__ __forceinline__ void gload_lds16(const void* g, void* l) {
    __builtin_amdgcn_global_load_lds(
        (const __attribute__((address_space(1))) unsigned int*)g,
        (__attribute__((address_space(3))) unsigned int*)l, 16, 0, 0);
}

#define WAIT_VM(N) asm volatile("s_waitcnt vmcnt(" #N ")" ::: "memory")

// ---------------- fp32 -> bf16 convert (8 elems/thread) ----------------
__global__ __launch_bounds__(256)
void cvt_kernel(const float* __restrict__ src, bf16* __restrict__ dst, int n8) {
    int i8 = blockIdx.x * 256 + threadIdx.x;
    if (i8 >= n8) return;
    const float* s = src + (size_t)i8 * 8;
    float4 x = *(const float4*)s;
    float4 y = *(const float4*)(s + 4);
    bf16x8 o;
    o[0] = (bf16)x.x; o[1] = (bf16)x.y; o[2] = (bf16)x.z; o[3] = (bf16)x.w;
    o[4] = (bf16)y.x; o[5] = (bf16)y.y; o[6] = (bf16)y.z; o[7] = (bf16)y.w;
    *(bf16x8*)(dst + (size_t)i8 * 8) = o;
}

// ---------------- LDS-tiled transpose+cvt: dst[C][R] = (bf16)src[R][C] ----------------
__global__ __launch_bounds__(256)
void transpose_cvt_kernel(const float* __restrict__ src, bf16* __restrict__ dst, int R, int C) {
    __shared__ bf16 tile[64][65];
    int tr0 = blockIdx.x * 64;   // row tile in src
    int tc0 = blockIdx.y * 64;   // col tile in src
    int tx = threadIdx.x & 63, ty = threadIdx.x >> 6;
#pragma unroll
    for (int j = 0; j < 16; j++) {
        int r = ty + j * 4;
        tile[tx][r] = (bf16)src[(size_t)(tr0 + r) * C + tc0 + tx];
    }
    __syncthreads();
#pragma unroll
    for (int j = 0; j < 16; j++) {
        int r = ty + j * 4;
        dst[(size_t)(tc0 + r) * R + tr0 + tx] = tile[r][tx];
    }
}

// ---------------- bias pack: biasf[0..3071]=bq|bk|bv, [3072..3199]=0, zbias[0..1023]=0 ----
__global__ __launch_bounds__(256)
void biaspack_kernel(const float* __restrict__ bq, const float* __restrict__ bk,
                     const float* __restrict__ bv, float* __restrict__ biasf,
                     float* __restrict__ zbias) {
    int i = blockIdx.x * 256 + threadIdx.x;
    if (i < 1024)      biasf[i] = bq[i];
    else if (i < 2048) biasf[i] = bk[i - 1024];
    else if (i < 3072) biasf[i] = bv[i - 2048];
    else if (i < 3200) biasf[i] = 0.f;
    else if (i < 4224) zbias[i - 3200] = 0.f;
}

// ---------------- composite bias: biasf[3072+j] = dot(bq, Wqa[:,j]) + bqa[j] ----------------
__global__ __launch_bounds__(64)
void compbias_kernel(const float* __restrict__ bq, const float* __restrict__ Wqa,
                     const float* __restrict__ bqa, float* __restrict__ out) {
    int j = threadIdx.x;
    float a = 0.f;
    for (int t = 0; t < 1024; t++) a += bq[t] * Wqa[(size_t)t * 64 + j];
    out[j] = a + bqa[j];
}

// ---------------- small GEMM (m97 structure), kept for ksc + comp-bias ----------
template<int BN, int WN, int EPI>
__global__ __launch_bounds__(WN * 128)
void gemm_kernel(const bf16* __restrict__ A, int lda,
                 const bf16* __restrict__ WT,
                 const float* __restrict__ bias,
                 void* __restrict__ Cout, int ldc,
                 const float* __restrict__ mask,
                 const bf16* __restrict__ qadd, int ldq,
                 int K) {
    constexpr int BM = 128;
    constexpr int NT = WN * 128;
    __shared__ bf16 As[BM * 32];
    __shared__ bf16 Bs[BN * 32];

    const int tid  = threadIdx.x;
    const int wid  = tid >> 6;
    const int lane = tid & 63;
    const int l16  = lane & 15;
    const int quad = lane >> 4;
    const int wm   = wid & 1;
    const int wn   = wid >> 1;
    const int m0   = blockIdx.x * BM;
    const int n0   = blockIdx.y * BN;

    floatx4 acc[4][4];
#pragma unroll
    for (int i = 0; i < 4; i++)
#pragma unroll
        for (int j = 0; j < 4; j++) acc[i][j] = (floatx4)0.0f;

    for (int k0 = 0; k0 < K; k0 += 32) {
        __syncthreads();
#pragma unroll
        for (int i = tid; i < BM * 4; i += NT) {
            const bf16* gp = A + (size_t)(m0 + (i >> 2)) * lda + k0 + (i & 3) * 8;
            gload_lds16(gp, (char*)As + (size_t)(i & ~63) * 16);
        }
#pragma unroll
        for (int i = tid; i < BN * 4; i += NT) {
            const bf16* gp = WT + (size_t)(n0 + (i >> 2)) * K + k0 + (i & 3) * 8;
            gload_lds16(gp, (char*)Bs + (size_t)(i & ~63) * 16);
        }
        __syncthreads();
        bf16x8 af[4], bfv[4];
#pragma unroll
        for (int mi = 0; mi < 4; mi++)
            af[mi] = *(const bf16x8*)&As[(wm * 64 + mi * 16 + l16) * 32 + quad * 8];
#pragma unroll
        for (int ni = 0; ni < 4; ni++)
            bfv[ni] = *(const bf16x8*)&Bs[(wn * 64 + ni * 16 + l16) * 32 + quad * 8];
#pragma unroll
        for (int mi = 0; mi < 4; mi++)
#pragma unroll
            for (int ni = 0; ni < 4; ni++)
                acc[mi][ni] = __builtin_amdgcn_mfma_f32_16x16x32_bf16(
                    af[mi], bfv[ni], acc[mi][ni], 0, 0, 0);
    }

#pragma unroll
    for (int mi = 0; mi < 4; mi++) {
#pragma unroll
        for (int ni = 0; ni < 4; ni++) {
            int col  = n0 + wn * 64 + ni * 16 + l16;
            int rowb = m0 + wm * 64 + mi * 16 + quad * 4;
            float bv = bias[col];
#pragma unroll
            for (int e = 0; e < 4; e++) {
                int row = rowb + e;
                float v = acc[mi][ni][e] + bv;
                if (EPI == 0) {
                    ((bf16*)Cout)[(size_t)row * ldc + col] = (bf16)v;
                } else if (EPI == 2) {
                    ((float*)Cout)[(size_t)row * ldc + col] = v * 0.125f + mask[row];
                } else {
                    v += (float)qadd[(size_t)row * ldq + col];
                    ((float*)Cout)[(size_t)row * ldc + col] = v;
                }
            }
        }
    }
}

// ---------------- 256x128 GEMM v4: BK=32, 3-slot LDS rotation, 2 blocks/CU ----------
// Mechanism change vs v2/v3 (both ~40% MfmaUtil at 1 block/CU): TLP. 72 KiB LDS +
// <=128 VGPR -> 2 blocks/CU, 4 waves/SIMD; cross-block overlap hides barrier/vmcnt
// convoys (m114). One barrier per K-step (33 total vs 128). Counted vmcnt(3):
// staging always 2 steps ahead, never drained in-loop.
// LDS slot (24576 B): A 16 subtiles x 1KB @0, B 8 subtiles x 1KB @16384.
// st_16x32 swizzle pair unchanged (inverse-swizzled global src + swizzled ds_read).
// Hazard ledger: stage(t+2)->slot[(t-1)%3], whose last reads were in step t-1,
// >=1 barrier earlier. vmcnt(3)@end(t) ensures stage(t+1) landed (stage(t+2) stays
// in flight). Per-output K accumulation order identical to v2/v3 -> same numerics.
#define STG(KT) do {                                                       \
    gload_lds16(gA0 + (KT) * 32, sA + ((KT) % 3) * 24576);                 \
    gload_lds16(gA1 + (KT) * 32, sA + ((KT) % 3) * 24576 + 1024);          \
    gload_lds16(gB0 + (KT) * 32, sB + ((KT) % 3) * 24576); } while (0)

#define RDF(SLOT) {                                                        \
    _Pragma("unroll") for (int i_ = 0; i_ < 4; ++i_)                       \
        af[i_] = *(const bf16x8*)(lA + (SLOT) * 24576 + i_ * 1024);        \
    _Pragma("unroll") for (int i_ = 0; i_ < 4; ++i_)                       \
        bq_[i_] = *(const bf16x8*)(lB + (SLOT) * 24576 + i_ * 1024); }

#define MM() {                                                             \
    _Pragma("unroll") for (int mi_ = 0; mi_ < 4; ++mi_)                    \
    _Pragma("unroll") for (int ni_ = 0; ni_ < 4; ++ni_)                    \
        acc[mi_][ni_] = __builtin_amdgcn_mfma_f32_16x16x32_bf16(           \
            af[mi_], bq_[ni_], acc[mi_][ni_], 0, 0, 0); }

template<int EPI>
__global__ __launch_bounds__(512, 4)
void gemm256_kernel(const bf16* __restrict__ A, int lda,
                    const bf16* __restrict__ B, int ldb,
                    const float* __restrict__ bias,
                    void* __restrict__ Cout, int ldc, int ncols,
                    const bf16* __restrict__ qadd, int ldq,
                    int ntn) {
    constexpr int NT = 32;   // K = 1024 / BK=32
    extern __shared__ __align__(16) char smem[];
    const int tid  = threadIdx.x;
    const int wid  = tid >> 6;
    const int lane = tid & 63;
    const int l16  = lane & 15;
    const int quad = lane >> 4;
    const int wm   = wid >> 1;   // 0..3  (64-row band)
    const int wn   = wid & 1;    // 0..1  (64-col band)

    // XCD-aware swizzle (grids here are %8==0; identity otherwise)
    const int nwg  = gridDim.x * gridDim.y;
    const int orig = blockIdx.y * gridDim.x + blockIdx.x;
    int swz = orig;
    if ((nwg & 7) == 0) swz = (orig & 7) * (nwg >> 3) + (orig >> 3);
    const int m0 = (swz / ntn) * 256;
    const int n0 = (swz % ntn) * 128;

    // stage sources: A rows wid*32..+31 (2 gloads), B rows wid*16..+15 (1 gload)
    const int scol = ((lane & 3) ^ ((lane >> 5) << 1)) << 3;  // inverse-swizzled chunk
    const bf16* gA0 = A + (size_t)(m0 + wid * 32 + (lane >> 2)) * lda + scol;
    const bf16* gA1 = gA0 + (size_t)16 * lda;
    const bf16* gB0 = B + (size_t)(n0 + wid * 16 + (lane >> 2)) * ldb + scol;
    // stage LDS dests (wave-uniform base; HW adds lane*16)
    char* sA = smem + wid * 2048;
    char* sB = smem + 16384 + wid * 1024;
    // frag read bases (swizzled)
    const int aoff = (l16 * 64 + quad * 16) ^ ((l16 & 8) << 2);
    const char* lA = smem + wm * 4096 + aoff;
    const char* lB = smem + 16384 + wn * 4096 + aoff;

    floatx4 acc[4][4];
#pragma unroll
    for (int i = 0; i < 4; ++i)
#pragma unroll
        for (int j = 0; j < 4; ++j) acc[i][j] = (floatx4)0.0f;

    // prologue: stage steps 0,1; wait step 0 landed (step 1 stays in flight)
    STG(0); STG(1);
    WAIT_VM(3);
    __builtin_amdgcn_s_barrier();

#pragma unroll
    for (int t = 0; t < NT; ++t) {
        if (t + 2 < NT) STG(t + 2);
        bf16x8 af[4], bq_[4];
        RDF(t % 3);
        __builtin_amdgcn_s_setprio(1);
        MM();
        __builtin_amdgcn_s_setprio(0);
        if (t <= NT - 3)      { WAIT_VM(3); }   // stage(t+1) landed; (t+2) in flight
        else if (t == NT - 2) { WAIT_VM(0); }   // drain for final step
        if (t < NT - 1) __builtin_amdgcn_s_barrier();
    }

    // ---- epilogue ----
#pragma unroll
    for (int mi = 0; mi < 4; ++mi) {
#pragma unroll
        for (int ni = 0; ni < 4; ++ni) {
            int col  = n0 + wn * 64 + ni * 16 + l16;
            int rowb = m0 + wm * 64 + mi * 16 + quad * 4;
            if (col < ncols) {
                float bv = bias[col];
#pragma unroll
                for (int e = 0; e < 4; ++e) {
                    int row = rowb + e;
                    float v = acc[mi][ni][e] + bv;
                    if (EPI == 0) {
                        ((bf16*)Cout)[(size_t)row * ldc + col] = (bf16)v;
                    } else {
                        v += (float)qadd[(size_t)row * ldq + col];
                        ((float*)Cout)[(size_t)row * ldc + col] = v;
                    }
                }
            }
        }
    }
}

// ---------------- softmax over n: qw[b*64+hg][n], logits = qa(bf16 in qkv)*0.125+mask ----
__global__ __launch_bounds__(256)
void softmax_kernel(const bf16* __restrict__ qkv, const float* __restrict__ mask,
                    float* __restrict__ qw) {
    int bh = blockIdx.x;           // b*64 + hg
    int b = bh >> 6, hg = bh & 63;
    int tid = threadIdx.x;
    float xs[16];
    float mx = -1e30f;
#pragma unroll
    for (int j = 0; j < 16; j++) {
        int n = tid + j * 256;
        float x = (float)qkv[(size_t)(b * 4096 + n) * 3200 + 3072 + hg] * 0.125f
                  + mask[b * 4096 + n];
        xs[j] = x;
        mx = fmaxf(mx, x);
    }
    __shared__ float red[256];
    red[tid] = mx;
    __syncthreads();
    for (int s = 128; s > 0; s >>= 1) {
        if (tid < s) red[tid] = fmaxf(red[tid], red[tid + s]);
        __syncthreads();
    }
    mx = red[0];
    __syncthreads();
    float sum = 0.f;
#pragma unroll
    for (int j = 0; j < 16; j++) { xs[j] = __expf(xs[j] - mx); sum += xs[j]; }
    red[tid] = sum;
    __syncthreads();
    for (int s = 128; s > 0; s >>= 1) {
        if (tid < s) red[tid] += red[tid + s];
        __syncthreads();
    }
    float inv = 1.0f / red[0];
#pragma unroll
    for (int j = 0; j < 16; j++)
        qw[(size_t)bh * 4096 + tid + j * 256] = xs[j] * inv;
}

// ---------------- gq stage1: partial[bh][ch][g][d] = sum_{n in chunk} qw*q ----------------
__global__ __launch_bounds__(256)
void gq1_kernel(const float* __restrict__ qw, const bf16* __restrict__ qkv,
                float* __restrict__ part) {
    int bh = blockIdx.x, ch = blockIdx.y;
    int b = bh >> 4, h = bh & 15;
    int tid = threadIdx.x;
    int g = tid >> 6, d = tid & 63;
    const float* wrow = qw + ((size_t)(b * 64 + h * 4 + g)) * 4096 + ch * 256;
    const bf16* qcol  = qkv + (size_t)(b * 4096 + ch * 256) * 3200 + h * 64 + d;
    float a = 0.f;
#pragma unroll 8
    for (int n = 0; n < 256; n++)
        a += wrow[n] * (float)qcol[(size_t)n * 3200];
    part[(((size_t)bh * 16 + ch) * 4 + g) * 64 + d] = a;
}

// ---------------- gk stage1: scalars from ksc[row][64] ----------------
__global__ __launch_bounds__(256)
void gk1_kernel(const float* __restrict__ ksc, const bf16* __restrict__ qkv,
                float* __restrict__ part) {
    int bh = blockIdx.x, ch = blockIdx.y;
    int b = bh >> 4, h = bh & 15;
    int tid = threadIdx.x;
    int g = tid >> 6, d = tid & 63;
    const float* sbase = ksc + (size_t)(b * 4096 + ch * 256) * 64 + h * 4 + g;
    const bf16* kcol   = qkv + (size_t)(b * 4096 + ch * 256) * 3200 + 1024 + h * 64 + d;
    float a = 0.f;
#pragma unroll 8
    for (int n = 0; n < 256; n++)
        a += sbase[(size_t)n * 64] * (float)kcol[(size_t)n * 3200];
    part[(((size_t)bh * 16 + ch) * 4 + g) * 64 + d] = a;
}

// ---------------- stage2: sum 16 chunks, then max/min over g ----------------
__global__ __launch_bounds__(256)
void gred_kernel(const float* __restrict__ part,
                 float* __restrict__ gmax, float* __restrict__ gmin) {
    int bh = blockIdx.x;
    int tid = threadIdx.x;
    int g = tid >> 6, d = tid & 63;
    float a = 0.f;
#pragma unroll
    for (int c = 0; c < 16; c++)
        a += part[(((size_t)bh * 16 + c) * 4 + g) * 64 + d];
    __shared__ float sg[4][64];
    sg[g][d] = a;
    __syncthreads();
    if (tid < 64) {
        float mx = sg[0][tid], mn = sg[0][tid];
#pragma unroll
        for (int gg = 1; gg < 4; gg++) {
            mx = fmaxf(mx, sg[gg][tid]);
            mn = fminf(mn, sg[gg][tid]);
        }
        gmax[bh * 64 + tid] = mx;
        gmin[bh * 64 + tid] = mn;
    }
}

// ---------------- elementwise: dst[row][c] = x>=0 ? x*gmax : x*gmin ----------------
__global__ __launch_bounds__(256)
void maxg_kernel(const bf16* __restrict__ qkv, int coloff,
                 const float* __restrict__ gmax, const float* __restrict__ gmin,
                 bf16* __restrict__ dst) {
    size_t i8 = (size_t)blockIdx.x * 256 + threadIdx.x;
    size_t e0 = i8 * 8;
    int row = (int)(e0 >> 10);
    int c   = (int)(e0 & 1023);
    int b   = row >> 12;
    bf16x8 kv = *(const bf16x8*)(qkv + (size_t)row * 3200 + coloff + c);
    bf16x8 out;
#pragma unroll
    for (int j = 0; j < 8; j++) {
        float f  = (float)kv[j];
        float gm = gmax[b * 1024 + c + j];
        float gn = gmin[b * 1024 + c + j];
        out[j] = (bf16)(f >= 0.f ? f * gm : f * gn);
    }
    *(bf16x8*)(dst + e0) = out;
}

extern "C" void kernel_launch(void* const* d_in, const int* in_sizes, int n_in,
                              void* d_out, int out_size, void* d_ws, size_t ws_size,
                              hipStream_t stream) {
    const float* hs   = (const float*)d_in[0];
    const float* mask = (const float*)d_in[1];
    const float* Wq   = (const float*)d_in[2];
    const float* bq   = (const float*)d_in[3];
    const float* Wqa  = (const float*)d_in[4];
    const float* bqa  = (const float*)d_in[5];
    const float* Wk   = (const float*)d_in[6];
    const float* bk   = (const float*)d_in[7];
    const float* Wka  = (const float*)d_in[8];
    const float* bka  = (const float*)d_in[9];
    const float* Wv   = (const float*)d_in[10];
    const float* bv   = (const float*)d_in[11];
    const float* Wt   = (const float*)d_in[12];
    const float* bt   = (const float*)d_in[13];

    char* p = (char*)d_ws;
    auto alloc = [&](size_t bytes) {
        char* r = p;
        p += (bytes + 255) & ~(size_t)255;
        return (void*)r;
    };
    bf16*  WT    = (bf16*) alloc((size_t)3328 * 1024 * 2);  // [Wq|Wk|Wv|comp|pad]^T, 3328 = 26*128
    bf16*  WqBf  = (bf16*) alloc((size_t)1024 * 1024 * 2);
    bf16*  WqaT  = (bf16*) alloc((size_t)128 * 1024 * 2);
    bf16*  WkaT  = (bf16*) alloc((size_t)64 * 1024 * 2);
    bf16*  WtT   = (bf16*) alloc((size_t)1024 * 1024 * 2);
    float* biasf = (float*)alloc((size_t)3200 * 4);
    float* zbias = (float*)alloc((size_t)1024 * 4);
    bf16*  qkv   = (bf16*) alloc((size_t)32768 * 3200 * 2);
    bf16*  hsb   = (bf16*) alloc((size_t)32768 * 1024 * 2); // aliased later as qk_u
    float* qw    = (float*)alloc((size_t)512 * 4096 * 4);   // aliased later as ksc
    float* part  = (float*)alloc((size_t)128 * 16 * 256 * 4);
    float* gqmax = (float*)alloc((size_t)8192 * 4);
    float* gqmin = (float*)alloc((size_t)8192 * 4);
    float* gkmax = (float*)alloc((size_t)8192 * 4);
    float* gkmin = (float*)alloc((size_t)8192 * 4);
    bf16*  qk_u  = hsb;            // hs_bf16 dead after QKV GEMM
    float* ksc   = qw;             // qw dead after gq stage1

    (void)hipFuncSetAttribute(reinterpret_cast<const void*>(&gemm256_kernel<0>),
                              hipFuncAttributeMaxDynamicSharedMemorySize, 73728);
    (void)hipFuncSetAttribute(reinterpret_cast<const void*>(&gemm256_kernel<3>),
                              hipFuncAttributeMaxDynamicSharedMemorySize, 73728);

    // --- prep ---
    cvt_kernel<<<16384, 256, 0, stream>>>(hs, hsb, 4194304);
    cvt_kernel<<<512, 256, 0, stream>>>(Wq, WqBf, 131072);
    transpose_cvt_kernel<<<dim3(16, 16), 256, 0, stream>>>(Wq, WT, 1024, 1024);
    transpose_cvt_kernel<<<dim3(16, 16), 256, 0, stream>>>(Wk, WT + (size_t)1024 * 1024, 1024, 1024);
    transpose_cvt_kernel<<<dim3(16, 16), 256, 0, stream>>>(Wv, WT + (size_t)2048 * 1024, 1024, 1024);
    transpose_cvt_kernel<<<dim3(16, 1), 256, 0, stream>>>(Wqa, WqaT, 1024, 64);
    transpose_cvt_kernel<<<dim3(16, 1), 256, 0, stream>>>(Wka, WkaT, 1024, 64);
    transpose_cvt_kernel<<<dim3(16, 16), 256, 0, stream>>>(Wt, WtT, 1024, 1024);
    biaspack_kernel<<<17, 256, 0, stream>>>(bq, bk, bv, biasf, zbias);
    compbias_kernel<<<1, 64, 0, stream>>>(bq, Wqa, bqa, biasf + 3072);
    // comp^T -> WT rows 3072..3199 (rows>=64 junk, unused)
    gemm_kernel<128, 2, 0><<<dim3(1, 8), 256, 0, stream>>>(
        WqaT, 1024, WqBf, zbias, WT + (size_t)3072 * 1024, 1024, nullptr, nullptr, 0, 1024);

    // --- main pipeline ---
    // qkv|qa = hsb @ WT^T + biasf  (M=32768, N=3200 padded to 3328, K=1024)
    gemm256_kernel<0><<<dim3(128, 26), 512, 73728, stream>>>(
        hsb, 1024, WT, 1024, biasf, qkv, 3200, 3200, nullptr, 0, 26);
    softmax_kernel<<<512, 256, 0, stream>>>(qkv, mask, qw);
    gq1_kernel<<<dim3(128, 16), 256, 0, stream>>>(qw, qkv, part);
    gred_kernel<<<128, 256, 0, stream>>>(part, gqmax, gqmin);
    maxg_kernel<<<16384, 256, 0, stream>>>(qkv, 1024, gqmax, gqmin, qk_u);
    // ksc = (qk @ Wka + bka)*0.125 + mask
    gemm_kernel<64, 1, 2><<<dim3(256, 1), 128, 0, stream>>>(
        qk_u, 1024, WkaT, bka, ksc, 64, mask, nullptr, 0, 1024);
    gk1_kernel<<<dim3(128, 16), 256, 0, stream>>>(ksc, qkv, part);
    gred_kernel<<<128, 256, 0, stream>>>(part, gkmax, gkmin);
    maxg_kernel<<<16384, 256, 0, stream>>>(qkv, 2048, gkmax, gkmin, qk_u);
    // out = u @ Wt + bt + q
    gemm256_kernel<3><<<dim3(128, 8), 512, 73728, stream>>>(
        qk_u, 1024, WtT, 1024, bt, d_out, 1024, 1024, qkv, 3200, 8);
}

// Round 6
// 883.675 us; speedup vs baseline: 1.0373x; 1.0373x over previous
//
#include <hip/hip_runtime.h>
#include <hip/hip_bf16.h>

typedef __bf16 bf16;
typedef __attribute__((ext_vector_type(8))) __bf16 bf16x8;
typedef __attribute__((ext_vector_type(4))) float floatx4;

// B=8, N=4096, DM=1024, H=16, G=4, D=64; rows = 32768
// Inputs fp32; compute bf16 MFMA; output fp32.
// qkv layout: [row][3200] = q(0..1023)|k(1024..2047)|v(2048..3071)|qa(3072..3135)|pad

__device__ __forceinline__ void gload_lds16(const void* g, void* l) {
    __builtin_amdgcn_global_load_lds(
        (const __attribute__((address_space(1))) unsigned int*)g,
        (__attribute__((address_space(3))) unsigned int*)l, 16, 0, 0);
}

#define WAIT_LGKM0() asm volatile("s_waitcnt lgkmcnt(0)" ::: "memory")
#define WAIT_VM(N) asm volatile("s_waitcnt vmcnt(" #N ")" ::: "memory")

// ---------------- fp32 -> bf16 convert (8 elems/thread) ----------------
__global__ __launch_bounds__(256)
void cvt_kernel(const float* __restrict__ src, bf16* __restrict__ dst, int n8) {
    int i8 = blockIdx.x * 256 + threadIdx.x;
    if (i8 >= n8) return;
    const float* s = src + (size_t)i8 * 8;
    float4 x = *(const float4*)s;
    float4 y = *(const float4*)(s + 4);
    bf16x8 o;
    o[0] = (bf16)x.x; o[1] = (bf16)x.y; o[2] = (bf16)x.z; o[3] = (bf16)x.w;
    o[4] = (bf16)y.x; o[5] = (bf16)y.y; o[6] = (bf16)y.z; o[7] = (bf16)y.w;
    *(bf16x8*)(dst + (size_t)i8 * 8) = o;
}

// ---------------- LDS-tiled transpose+cvt: dst[C][R] = (bf16)src[R][C] ----------------
__global__ __launch_bounds__(256)
void transpose_cvt_kernel(const float* __restrict__ src, bf16* __restrict__ dst, int R, int C) {
    __shared__ bf16 tile[64][65];
    int tr0 = blockIdx.x * 64;   // row tile in src
    int tc0 = blockIdx.y * 64;   // col tile in src
    int tx = threadIdx.x & 63, ty = threadIdx.x >> 6;
#pragma unroll
    for (int j = 0; j < 16; j++) {
        int r = ty + j * 4;
        tile[tx][r] = (bf16)src[(size_t)(tr0 + r) * C + tc0 + tx];
    }
    __syncthreads();
#pragma unroll
    for (int j = 0; j < 16; j++) {
        int r = ty + j * 4;
        dst[(size_t)(tc0 + r) * R + tr0 + tx] = tile[r][tx];
    }
}

// ---------------- bias pack: biasf[0..3071]=bq|bk|bv, [3072..3199]=0, zbias[0..1023]=0 ----
__global__ __launch_bounds__(256)
void biaspack_kernel(const float* __restrict__ bq, const float* __restrict__ bk,
                     const float* __restrict__ bv, float* __restrict__ biasf,
                     float* __restrict__ zbias) {
    int i = blockIdx.x * 256 + threadIdx.x;
    if (i < 1024)      biasf[i] = bq[i];
    else if (i < 2048) biasf[i] = bk[i - 1024];
    else if (i < 3072) biasf[i] = bv[i - 2048];
    else if (i < 3200) biasf[i] = 0.f;
    else if (i < 4224) zbias[i - 3200] = 0.f;
}

// ---------------- composite bias: biasf[3072+j] = dot(bq, Wqa[:,j]) + bqa[j] ----------------
__global__ __launch_bounds__(64)
void compbias_kernel(const float* __restrict__ bq, const float* __restrict__ Wqa,
                     const float* __restrict__ bqa, float* __restrict__ out) {
    int j = threadIdx.x;
    float a = 0.f;
    for (int t = 0; t < 1024; t++) a += bq[t] * Wqa[(size_t)t * 64 + j];
    out[j] = a + bqa[j];
}

// ---------------- small GEMM (m97 structure), kept for comp-bias ----------
template<int BN, int WN, int EPI>
__global__ __launch_bounds__(WN * 128)
void gemm_kernel(const bf16* __restrict__ A, int lda,
                 const bf16* __restrict__ WT,
                 const float* __restrict__ bias,
                 void* __restrict__ Cout, int ldc,
                 const float* __restrict__ mask,
                 const bf16* __restrict__ qadd, int ldq,
                 int K) {
    constexpr int BM = 128;
    constexpr int NT = WN * 128;
    __shared__ bf16 As[BM * 32];
    __shared__ bf16 Bs[BN * 32];

    const int tid  = threadIdx.x;
    const int wid  = tid >> 6;
    const int lane = tid & 63;
    const int l16  = lane & 15;
    const int quad = lane >> 4;
    const int wm   = wid & 1;
    const int wn   = wid >> 1;
    const int m0   = blockIdx.x * BM;
    const int n0   = blockIdx.y * BN;

    floatx4 acc[4][4];
#pragma unroll
    for (int i = 0; i < 4; i++)
#pragma unroll
        for (int j = 0; j < 4; j++) acc[i][j] = (floatx4)0.0f;

    for (int k0 = 0; k0 < K; k0 += 32) {
        __syncthreads();
#pragma unroll
        for (int i = tid; i < BM * 4; i += NT) {
            const bf16* gp = A + (size_t)(m0 + (i >> 2)) * lda + k0 + (i & 3) * 8;
            gload_lds16(gp, (char*)As + (size_t)(i & ~63) * 16);
        }
#pragma unroll
        for (int i = tid; i < BN * 4; i += NT) {
            const bf16* gp = WT + (size_t)(n0 + (i >> 2)) * K + k0 + (i & 3) * 8;
            gload_lds16(gp, (char*)Bs + (size_t)(i & ~63) * 16);
        }
        __syncthreads();
        bf16x8 af[4], bfv[4];
#pragma unroll
        for (int mi = 0; mi < 4; mi++)
            af[mi] = *(const bf16x8*)&As[(wm * 64 + mi * 16 + l16) * 32 + quad * 8];
#pragma unroll
        for (int ni = 0; ni < 4; ni++)
            bfv[ni] = *(const bf16x8*)&Bs[(wn * 64 + ni * 16 + l16) * 32 + quad * 8];
#pragma unroll
        for (int mi = 0; mi < 4; mi++)
#pragma unroll
            for (int ni = 0; ni < 4; ni++)
                acc[mi][ni] = __builtin_amdgcn_mfma_f32_16x16x32_bf16(
                    af[mi], bfv[ni], acc[mi][ni], 0, 0, 0);
    }

#pragma unroll
    for (int mi = 0; mi < 4; mi++) {
#pragma unroll
        for (int ni = 0; ni < 4; ni++) {
            int col  = n0 + wn * 64 + ni * 16 + l16;
            int rowb = m0 + wm * 64 + mi * 16 + quad * 4;
            float bv = bias[col];
#pragma unroll
            for (int e = 0; e < 4; e++) {
                int row = rowb + e;
                float v = acc[mi][ni][e] + bv;
                if (EPI == 0) {
                    ((bf16*)Cout)[(size_t)row * ldc + col] = (bf16)v;
                } else if (EPI == 2) {
                    ((float*)Cout)[(size_t)row * ldc + col] = v * 0.125f + mask[row];
                } else {
                    v += (float)qadd[(size_t)row * ldq + col];
                    ((float*)Cout)[(size_t)row * ldc + col] = v;
                }
            }
        }
    }
}

// ---------------- ksc GEMM with fused maxg1: A = transform(qkv k-cols) ----------------
// ksc[row][j] = (sum_k qk[row][k]*Wka[k][j] + bka[j])*0.125 + mask[row]
// qk[row][k] = f>=0 ? f*gqmax[b][k] : f*gqmin[b][k],  f = qkv[row][1024+k] (bf16)
// Transform produces bit-identical bf16 values to the old maxg1 kernel.
__global__ __launch_bounds__(128)
void gemmksc_kernel(const bf16* __restrict__ qkv,
                    const bf16* __restrict__ WT,   // WkaT [64][1024]
                    const float* __restrict__ bias,
                    float* __restrict__ Cout,      // ksc [32768][64]
                    const float* __restrict__ mask,
                    const float* __restrict__ gmax,
                    const float* __restrict__ gmin) {
    constexpr int BM = 128, BN = 64;
    __shared__ bf16 As[BM * 32];
    __shared__ bf16 Bs[BN * 32];
    const int tid  = threadIdx.x;
    const int wid  = tid >> 6;
    const int lane = tid & 63;
    const int l16  = lane & 15;
    const int quad = lane >> 4;
    const int wm   = wid & 1;
    const int m0   = blockIdx.x * BM;
    const int bb   = m0 >> 12;   // batch, uniform per block (128 | 4096)

    floatx4 acc[4][4];
#pragma unroll
    for (int i = 0; i < 4; i++)
#pragma unroll
        for (int j = 0; j < 4; j++) acc[i][j] = (floatx4)0.0f;

    for (int k0 = 0; k0 < 1024; k0 += 32) {
        __syncthreads();
#pragma unroll
        for (int i = tid; i < BM * 4; i += 128) {
            int row = m0 + (i >> 2);
            int col = k0 + (i & 3) * 8;
            bf16x8 kv = *(const bf16x8*)(qkv + (size_t)row * 3200 + 1024 + col);
            float4 gm0 = *(const float4*)(gmax + bb * 1024 + col);
            float4 gm1 = *(const float4*)(gmax + bb * 1024 + col + 4);
            float4 gn0 = *(const float4*)(gmin + bb * 1024 + col);
            float4 gn1 = *(const float4*)(gmin + bb * 1024 + col + 4);
            float gms[8] = {gm0.x, gm0.y, gm0.z, gm0.w, gm1.x, gm1.y, gm1.z, gm1.w};
            float gns[8] = {gn0.x, gn0.y, gn0.z, gn0.w, gn1.x, gn1.y, gn1.z, gn1.w};
            bf16x8 o;
#pragma unroll
            for (int j = 0; j < 8; ++j) {
                float f = (float)kv[j];
                o[j] = (bf16)(f >= 0.f ? f * gms[j] : f * gns[j]);
            }
            *(bf16x8*)((char*)As + (size_t)i * 16) = o;
        }
#pragma unroll
        for (int i = tid; i < BN * 4; i += 128) {
            const bf16* gp = WT + (size_t)(i >> 2) * 1024 + k0 + (i & 3) * 8;
            gload_lds16(gp, (char*)Bs + (size_t)(i & ~63) * 16);
        }
        __syncthreads();
        bf16x8 af[4], bfv[4];
#pragma unroll
        for (int mi = 0; mi < 4; mi++)
            af[mi] = *(const bf16x8*)&As[(wm * 64 + mi * 16 + l16) * 32 + quad * 8];
#pragma unroll
        for (int ni = 0; ni < 4; ni++)
            bfv[ni] = *(const bf16x8*)&Bs[(ni * 16 + l16) * 32 + quad * 8];
#pragma unroll
        for (int mi = 0; mi < 4; mi++)
#pragma unroll
            for (int ni = 0; ni < 4; ni++)
                acc[mi][ni] = __builtin_amdgcn_mfma_f32_16x16x32_bf16(
                    af[mi], bfv[ni], acc[mi][ni], 0, 0, 0);
    }

#pragma unroll
    for (int mi = 0; mi < 4; mi++) {
#pragma unroll
        for (int ni = 0; ni < 4; ni++) {
            int col  = ni * 16 + l16;
            int rowb = m0 + wm * 64 + mi * 16 + quad * 4;
            float bv = bias[col];
#pragma unroll
            for (int e = 0; e < 4; e++) {
                int row = rowb + e;
                Cout[(size_t)row * 64 + col] = (acc[mi][ni][e] + bv) * 0.125f + mask[row];
            }
        }
    }
}

// ---------------- 256x256 8-phase GEMM (r2 structure, proven best) ----------------
// QA=1: epilogue also emits qaT[b*64+hg][n] = v*0.125+mask for cols 3072..3135
// (pre-bf16-rounding f32 -> closer to reference than the old bf16 round-trip).
#define DO_MFMA(MH, NH)                                                              \
    _Pragma("unroll")                                                                \
    for (int r_ = 0; r_ < 4; ++r_) {                                                 \
        _Pragma("unroll")                                                            \
        for (int nj_ = 0; nj_ < 2; ++nj_) {                                          \
            _Pragma("unroll")                                                        \
            for (int kk_ = 0; kk_ < 2; ++kk_) {                                      \
                acc[(MH) * 4 + r_][(NH) * 2 + nj_] =                                 \
                    __builtin_amdgcn_mfma_f32_16x16x32_bf16(                         \
                        af[r_][kk_], bfv[(NH) * 2 + nj_][kk_],                       \
                        acc[(MH) * 4 + r_][(NH) * 2 + nj_], 0, 0, 0);                \
            }                                                                        \
        }                                                                            \
    }

#define LOAD_A(MQ, BS)                                                               \
    _Pragma("unroll")                                                                \
    for (int r_ = 0; r_ < 4; ++r_)                                                   \
        _Pragma("unroll")                                                            \
        for (int kk_ = 0; kk_ < 2; ++kk_)                                            \
            af[r_][kk_] = *(const bf16x8*)(lA + (BS) + (MQ) * 8192 + r_ * 2048 + kk_ * 1024);

#define LOAD_B(NQ, BS)                                                               \
    _Pragma("unroll")                                                                \
    for (int nj_ = 0; nj_ < 2; ++nj_)                                                \
        _Pragma("unroll")                                                            \
        for (int kk_ = 0; kk_ < 2; ++kk_)                                            \
            bfv[(NQ) * 2 + nj_][kk_] =                                               \
                *(const bf16x8*)(lB + (BS) + (NQ) * 4096 + nj_ * 2048 + kk_ * 1024);

#define STAGE_A(H, KT, P) do {                                                       \
    gload_lds16(gA##H##0 + (KT) * 128, smem + (P) * 32768 + (H) * 16384 + ldsc);     \
    gload_lds16(gA##H##1 + (KT) * 128, smem + (P) * 32768 + (H) * 16384 + 8192 + ldsc); \
} while (0)

#define STAGE_B(H, KT, P) do {                                                       \
    gload_lds16(gB##H##0 + (KT) * 128, smem + 65536 + (P) * 32768 + (H) * 16384 + ldsc); \
    gload_lds16(gB##H##1 + (KT) * 128, smem + 65536 + (P) * 32768 + (H) * 16384 + 8192 + ldsc); \
} while (0)

template<int EPI, int QA>
__global__ __launch_bounds__(512, 2)
void gemm256_kernel(const bf16* __restrict__ A, int lda,
                    const bf16* __restrict__ B, int ldb,
                    const float* __restrict__ bias,
                    void* __restrict__ Cout, int ldc, int ncols,
                    const bf16* __restrict__ qadd, int ldq,
                    int ntn,
                    const float* __restrict__ mask,
                    float* __restrict__ qaT) {
    constexpr int NTILES = 16;
    extern __shared__ __align__(16) char smem[];
    const int tid  = threadIdx.x;
    const int wid  = tid >> 6;
    const int lane = tid & 63;
    const int l16  = lane & 15;
    const int quad = lane >> 4;
    const int wm   = wid >> 2;   // 0..1
    const int wn   = wid & 3;    // 0..3

    // XCD-aware swizzle (grids here are %8==0; identity otherwise)
    const int nwg  = gridDim.x * gridDim.y;
    const int orig = blockIdx.y * gridDim.x + blockIdx.x;
    int swz = orig;
    if ((nwg & 7) == 0) swz = (orig & 7) * (nwg >> 3) + (orig >> 3);
    const int m0 = (swz / ntn) * 256;
    const int n0 = (swz % ntn) * 256;

    // ---- per-thread constants ----
    const int w2   = wid >> 1;                                  // 0..3
    const int cg   = wid & 1;                                   // 0..1
    const int lrow = lane >> 2;                                 // 0..15
    const int lcb8 = ((lane & 3) ^ ((lane >> 5) << 1)) << 3;    // inverse-swizzled k elems
    const int ldsc = w2 * 2048 + cg * 1024;                     // LDS dest within (h,j) block
    const int aoff = (l16 * 64 + quad * 16) ^ ((l16 & 8) << 2); // swizzled read offset

    const char* gA00 = (const char*)A + ((size_t)(m0 + w2 * 16 + lrow) * lda + (cg << 5) + lcb8) * 2;
    const char* gA01 = gA00 + (size_t)64 * lda * 2;
    const char* gA10 = gA00 + (size_t)128 * lda * 2;
    const char* gA11 = gA00 + (size_t)192 * lda * 2;
    const char* gB00 = (const char*)B + ((size_t)(n0 + w2 * 16 + lrow) * ldb + (cg << 5) + lcb8) * 2;
    const char* gB01 = gB00 + (size_t)64 * ldb * 2;
    const char* gB10 = gB00 + (size_t)128 * ldb * 2;
    const char* gB11 = gB00 + (size_t)192 * ldb * 2;

    const char* lA = smem + wm * 16384 + aoff;
    const char* lB = smem + 65536 + wn * 8192 + aoff;

    floatx4 acc[8][4];
#pragma unroll
    for (int i = 0; i < 8; ++i)
#pragma unroll
        for (int j = 0; j < 4; ++j) acc[i][j] = (floatx4)0.0f;

    // prologue: B(0), A(0), B(1) -> vmcnt(4): tile0 landed, B(1) in flight
    STAGE_B(0, 0, 0);
    STAGE_B(1, 0, 0);
    STAGE_A(0, 0, 0);
    STAGE_A(1, 0, 0);
    STAGE_B(0, 1, 1);
    STAGE_B(1, 1, 1);
    WAIT_VM(4);
    __builtin_amdgcn_s_barrier();

#pragma unroll
    for (int t = 0; t < NTILES; ++t) {
        bf16x8 af[4][2], bfv[4][2];

        // ---- phase 0: read A(mq=0) + B(nq=0); stage A0(t+1) ----
        LOAD_A(0, (t & 1) * 32768)
        LOAD_B(0, (t & 1) * 32768)
        if (t + 1 < NTILES) STAGE_A(0, t + 1, (t + 1) & 1);
        __builtin_amdgcn_s_barrier();
        WAIT_LGKM0();
        __builtin_amdgcn_s_setprio(1);
        DO_MFMA(0, 0)
        __builtin_amdgcn_s_setprio(0);
        __builtin_amdgcn_s_barrier();

        // ---- phase 1: read B(nq=1); stage A1(t+1) ----
        LOAD_B(1, (t & 1) * 32768)
        if (t + 1 < NTILES) STAGE_A(1, t + 1, (t + 1) & 1);
        __builtin_amdgcn_s_barrier();
        WAIT_LGKM0();
        __builtin_amdgcn_s_setprio(1);
        DO_MFMA(0, 1)
        __builtin_amdgcn_s_setprio(0);
        __builtin_amdgcn_s_barrier();

        // ---- phase 2: read A(mq=1); stage B0(t+2) ----
        LOAD_A(1, (t & 1) * 32768)
        if (t + 2 < NTILES) STAGE_B(0, t + 2, t & 1);
        __builtin_amdgcn_s_barrier();
        WAIT_LGKM0();
        __builtin_amdgcn_s_setprio(1);
        DO_MFMA(1, 0)
        __builtin_amdgcn_s_setprio(0);
        __builtin_amdgcn_s_barrier();

        // ---- phase 3: stage B1(t+2); tile-end counted wait ----
        if (t + 2 < NTILES) STAGE_B(1, t + 2, t & 1);
        __builtin_amdgcn_s_barrier();
        __builtin_amdgcn_s_setprio(1);
        DO_MFMA(1, 1)
        __builtin_amdgcn_s_setprio(0);
        if (t < NTILES - 2) {
            WAIT_VM(4);
            __builtin_amdgcn_s_barrier();
        } else if (t == NTILES - 2) {
            WAIT_VM(0);
            __builtin_amdgcn_s_barrier();
        }
    }

    // ---- epilogue ----
#pragma unroll
    for (int mi = 0; mi < 8; ++mi) {
#pragma unroll
        for (int ni = 0; ni < 4; ++ni) {
            int col  = n0 + wn * 64 + ni * 16 + l16;
            int rowb = m0 + wm * 128 + mi * 16 + quad * 4;
            if (col < ncols) {
                float bv = bias[col];
#pragma unroll
                for (int e = 0; e < 4; ++e) {
                    int row = rowb + e;
                    float v = acc[mi][ni][e] + bv;
                    if (EPI == 0) {
                        ((bf16*)Cout)[(size_t)row * ldc + col] = (bf16)v;
                        if (QA) {
                            if (col >= 3072 && col < 3136) {
                                qaT[(size_t)((row >> 12) * 64 + (col - 3072)) * 4096
                                    + (row & 4095)] = v * 0.125f + mask[row];
                            }
                        }
                    } else {
                        v += (float)qadd[(size_t)row * ldq + col];
                        ((float*)Cout)[(size_t)row * ldc + col] = v;
                    }
                }
            }
        }
    }
}

// ---------------- softmax over n (coalesced via qaT): qw[bh][n] ----------------
// NOTE: qaT may alias qw (in-place): each block reads its full row into registers
// before any write of that row; blocks own disjoint rows.
__global__ __launch_bounds__(256)
void softmax_kernel(const float* __restrict__ qaT, float* __restrict__ qw) {
    int bh = blockIdx.x;           // b*64 + hg
    int tid = threadIdx.x;
    const float* rowp = qaT + (size_t)bh * 4096;
    float xs[16];
    float mx = -1e30f;
#pragma unroll
    for (int j = 0; j < 16; j++) {
        float x = rowp[tid + j * 256];
        xs[j] = x;
        mx = fmaxf(mx, x);
    }
    __shared__ float red[256];
    red[tid] = mx;
    __syncthreads();
    for (int s = 128; s > 0; s >>= 1) {
        if (tid < s) red[tid] = fmaxf(red[tid], red[tid + s]);
        __syncthreads();
    }
    mx = red[0];
    __syncthreads();
    float sum = 0.f;
#pragma unroll
    for (int j = 0; j < 16; j++) { xs[j] = __expf(xs[j] - mx); sum += xs[j]; }
    red[tid] = sum;
    __syncthreads();
    for (int s = 128; s > 0; s >>= 1) {
        if (tid < s) red[tid] += red[tid + s];
        __syncthreads();
    }
    float inv = 1.0f / red[0];
#pragma unroll
    for (int j = 0; j < 16; j++)
        qw[(size_t)bh * 4096 + tid + j * 256] = xs[j] * inv;
}

// ---------------- gq stage1: partial[bh][ch][g][d] = sum_{n in chunk} qw*q ----------------
__global__ __launch_bounds__(256)
void gq1_kernel(const float* __restrict__ qw, const bf16* __restrict__ qkv,
                float* __restrict__ part) {
    int bh = blockIdx.x, ch = blockIdx.y;
    int b = bh >> 4, h = bh & 15;
    int tid = threadIdx.x;
    int g = tid >> 6, d = tid & 63;
    const float* wrow = qw + ((size_t)(b * 64 + h * 4 + g)) * 4096 + ch * 256;
    const bf16* qcol  = qkv + (size_t)(b * 4096 + ch * 256) * 3200 + h * 64 + d;
    float a = 0.f;
#pragma unroll 8
    for (int n = 0; n < 256; n++)
        a += wrow[n] * (float)qcol[(size_t)n * 3200];
    part[(((size_t)bh * 16 + ch) * 4 + g) * 64 + d] = a;
}

// ---------------- gk stage1: scalars from ksc[row][64] ----------------
__global__ __launch_bounds__(256)
void gk1_kernel(const float* __restrict__ ksc, const bf16* __restrict__ qkv,
                float* __restrict__ part) {
    int bh = blockIdx.x, ch = blockIdx.y;
    int b = bh >> 4, h = bh & 15;
    int tid = threadIdx.x;
    int g = tid >> 6, d = tid & 63;
    const float* sbase = ksc + (size_t)(b * 4096 + ch * 256) * 64 + h * 4 + g;
    const bf16* kcol   = qkv + (size_t)(b * 4096 + ch * 256) * 3200 + 1024 + h * 64 + d;
    float a = 0.f;
#pragma unroll 8
    for (int n = 0; n < 256; n++)
        a += sbase[(size_t)n * 64] * (float)kcol[(size_t)n * 3200];
    part[(((size_t)bh * 16 + ch) * 4 + g) * 64 + d] = a;
}

// ---------------- stage2: sum 16 chunks, then max/min over g ----------------
__global__ __launch_bounds__(256)
void gred_kernel(const float* __restrict__ part,
                 float* __restrict__ gmax, float* __restrict__ gmin) {
    int bh = blockIdx.x;
    int tid = threadIdx.x;
    int g = tid >> 6, d = tid & 63;
    float a = 0.f;
#pragma unroll
    for (int c = 0; c < 16; c++)
        a += part[(((size_t)bh * 16 + c) * 4 + g) * 64 + d];
    __shared__ float sg[4][64];
    sg[g][d] = a;
    __syncthreads();
    if (tid < 64) {
        float mx = sg[0][tid], mn = sg[0][tid];
#pragma unroll
        for (int gg = 1; gg < 4; gg++) {
            mx = fmaxf(mx, sg[gg][tid]);
            mn = fminf(mn, sg[gg][tid]);
        }
        gmax[bh * 64 + tid] = mx;
        gmin[bh * 64 + tid] = mn;
    }
}

// ---------------- elementwise: dst[row][c] = x>=0 ? x*gmax : x*gmin ----------------
__global__ __launch_bounds__(256)
void maxg_kernel(const bf16* __restrict__ qkv, int coloff,
                 const float* __restrict__ gmax, const float* __restrict__ gmin,
                 bf16* __restrict__ dst) {
    size_t i8 = (size_t)blockIdx.x * 256 + threadIdx.x;
    size_t e0 = i8 * 8;
    int row = (int)(e0 >> 10);
    int c   = (int)(e0 & 1023);
    int b   = row >> 12;
    bf16x8 kv = *(const bf16x8*)(qkv + (size_t)row * 3200 + coloff + c);
    bf16x8 out;
#pragma unroll
    for (int j = 0; j < 8; j++) {
        float f  = (float)kv[j];
        float gm = gmax[b * 1024 + c + j];
        float gn = gmin[b * 1024 + c + j];
        out[j] = (bf16)(f >= 0.f ? f * gm : f * gn);
    }
    *(bf16x8*)(dst + e0) = out;
}

extern "C" void kernel_launch(void* const* d_in, const int* in_sizes, int n_in,
                              void* d_out, int out_size, void* d_ws, size_t ws_size,
                              hipStream_t stream) {
    const float* hs   = (const float*)d_in[0];
    const float* mask = (const float*)d_in[1];
    const float* Wq   = (const float*)d_in[2];
    const float* bq   = (const float*)d_in[3];
    const float* Wqa  = (const float*)d_in[4];
    const float* bqa  = (const float*)d_in[5];
    const float* Wk   = (const float*)d_in[6];
    const float* bk   = (const float*)d_in[7];
    const float* Wka  = (const float*)d_in[8];
    const float* bka  = (const float*)d_in[9];
    const float* Wv   = (const float*)d_in[10];
    const float* bv   = (const float*)d_in[11];
    const float* Wt   = (const float*)d_in[12];
    const float* bt   = (const float*)d_in[13];

    char* p = (char*)d_ws;
    auto alloc = [&](size_t bytes) {
        char* r = p;
        p += (bytes + 255) & ~(size_t)255;
        return (void*)r;
    };
    bf16*  WT    = (bf16*) alloc((size_t)3328 * 1024 * 2);  // [Wq|Wk|Wv|comp|pad]^T, 3328 = 13*256
    bf16*  WqBf  = (bf16*) alloc((size_t)1024 * 1024 * 2);
    bf16*  WqaT  = (bf16*) alloc((size_t)128 * 1024 * 2);
    bf16*  WkaT  = (bf16*) alloc((size_t)64 * 1024 * 2);
    bf16*  WtT   = (bf16*) alloc((size_t)1024 * 1024 * 2);
    float* biasf = (float*)alloc((size_t)3200 * 4);
    float* zbias = (float*)alloc((size_t)1024 * 4);
    bf16*  qkv   = (bf16*) alloc((size_t)32768 * 3200 * 2);
    bf16*  hsb   = (bf16*) alloc((size_t)32768 * 1024 * 2); // aliased later as qk_u
    float* qw    = (float*)alloc((size_t)512 * 4096 * 4);   // aliased: qaT, then ksc
    float* part  = (float*)alloc((size_t)128 * 16 * 256 * 4);
    float* gqmax = (float*)alloc((size_t)8192 * 4);
    float* gqmin = (float*)alloc((size_t)8192 * 4);
    float* gkmax = (float*)alloc((size_t)8192 * 4);
    float* gkmin = (float*)alloc((size_t)8192 * 4);
    bf16*  qk_u  = hsb;            // hs_bf16 dead after QKV GEMM
    float* qaT   = qw;             // qa logits (in-place softmax: reads precede writes per row)
    float* ksc   = qw;             // qw dead after gq stage1

    (void)hipFuncSetAttribute(reinterpret_cast<const void*>(&gemm256_kernel<0, 1>),
                              hipFuncAttributeMaxDynamicSharedMemorySize, 131072);
    (void)hipFuncSetAttribute(reinterpret_cast<const void*>(&gemm256_kernel<3, 0>),
                              hipFuncAttributeMaxDynamicSharedMemorySize, 131072);

    // --- prep ---
    cvt_kernel<<<16384, 256, 0, stream>>>(hs, hsb, 4194304);
    cvt_kernel<<<512, 256, 0, stream>>>(Wq, WqBf, 131072);
    transpose_cvt_kernel<<<dim3(16, 16), 256, 0, stream>>>(Wq, WT, 1024, 1024);
    transpose_cvt_kernel<<<dim3(16, 16), 256, 0, stream>>>(Wk, WT + (size_t)1024 * 1024, 1024, 1024);
    transpose_cvt_kernel<<<dim3(16, 16), 256, 0, stream>>>(Wv, WT + (size_t)2048 * 1024, 1024, 1024);
    transpose_cvt_kernel<<<dim3(16, 1), 256, 0, stream>>>(Wqa, WqaT, 1024, 64);
    transpose_cvt_kernel<<<dim3(16, 1), 256, 0, stream>>>(Wka, WkaT, 1024, 64);
    transpose_cvt_kernel<<<dim3(16, 16), 256, 0, stream>>>(Wt, WtT, 1024, 1024);
    biaspack_kernel<<<17, 256, 0, stream>>>(bq, bk, bv, biasf, zbias);
    compbias_kernel<<<1, 64, 0, stream>>>(bq, Wqa, bqa, biasf + 3072);
    // comp^T -> WT rows 3072..3199 (rows>=64 junk, unused)
    gemm_kernel<128, 2, 0><<<dim3(1, 8), 256, 0, stream>>>(
        WqaT, 1024, WqBf, zbias, WT + (size_t)3072 * 1024, 1024, nullptr, nullptr, 0, 1024);

    // --- main pipeline ---
    // qkv|qa = hsb @ WT^T + biasf  (M=32768, N=3200 padded to 3328, K=1024); qaT fork
    gemm256_kernel<0, 1><<<dim3(128, 13), 512, 131072, stream>>>(
        hsb, 1024, WT, 1024, biasf, qkv, 3200, 3200, nullptr, 0, 13, mask, qaT);
    softmax_kernel<<<512, 256, 0, stream>>>(qaT, qw);
    gq1_kernel<<<dim3(128, 16), 256, 0, stream>>>(qw, qkv, part);
    gred_kernel<<<128, 256, 0, stream>>>(part, gqmax, gqmin);
    // ksc = (transform(k) @ Wka + bka)*0.125 + mask   (maxg1 fused into staging)
    gemmksc_kernel<<<256, 128, 0, stream>>>(qkv, WkaT, bka, ksc, mask, gqmax, gqmin);
    gk1_kernel<<<dim3(128, 16), 256, 0, stream>>>(ksc, qkv, part);
    gred_kernel<<<128, 256, 0, stream>>>(part, gkmax, gkmin);
    maxg_kernel<<<16384, 256, 0, stream>>>(qkv, 2048, gkmax, gkmin, qk_u);
    // out = u @ Wt + bt + q
    gemm256_kernel<3, 0><<<dim3(128, 4), 512, 131072, stream>>>(
        qk_u, 1024, WtT, 1024, bt, d_out, 1024, 1024, qkv, 3200, 4, nullptr, nullptr);
}